// Round 5
// baseline (152.221 us; speedup 1.0000x reference)
//
#include <hip/hip_runtime.h>
#include <hip/hip_cooperative_groups.h>

namespace cg = cooperative_groups;

#define ALPHA  0.7f
#define MARGIN 0.5f
#define TI   32    // i-tile height
#define TJW  256   // j-tile width = block width (JR=1)
#define GRID 1024  // 4 blocks/CU * 256 CU -- co-resident for grid.sync

// Single fused cooperative kernel.
// Triangular tiles: column jt (j in [jt*256,(jt+1)*256)) has i-tiles
// it = 0..8*jt+7 (32 rows each). K(jt) = 4*jt*(jt+1). T = 4*NJ*(NJ+1).
//   it <  8*jt -> full tile (all i < all j, no predicate)
//   it >= 8*jt -> partial   (per-pair i<j predicate)
// Each block grid-strides tiles tau = bid, bid+GRID, ... (fixed order ->
// deterministic FP sums), writes its partial to its own ws slot (no init
// needed), grid.sync(), block 0 reduces in fixed order.
__global__ __launch_bounds__(256, 4)
void fused_kernel(const float* __restrict__ p, const float* __restrict__ t,
                  int B, float* __restrict__ bsum, float* __restrict__ bmse,
                  int* __restrict__ bcnt, float* __restrict__ out) {
    __shared__ float rs[4], rm[4];
    __shared__ int   rc[4];
    __shared__ double ds[4], dm[4];
    __shared__ long long dc[4];

    const int tid = threadIdx.x;
    const int bid = blockIdx.x;
    const int wid = tid >> 6, lane = tid & 63;
    const int NJ = (B + TJW - 1) / TJW;
    const int T  = 4 * NJ * (NJ + 1);

    float sacc = 0.0f, macc = 0.0f;
    int   cacc = 0;

    for (int tau = bid; tau < T; tau += GRID) {
        int jt = (int)((sqrtf((float)tau + 1.0f) - 1.0f) * 0.5f);
        while (4 * (jt + 1) * (jt + 2) <= tau) ++jt;
        while (4 * jt * (jt + 1) > tau) --jt;
        const int it    = tau - 4 * jt * (jt + 1);
        const int ibase = it * TI;
        const int jg    = jt * TJW + tid;
        const bool jv   = jg < B;
        const float tj  = jv ? t[jg] : 0.0f;
        const float pj  = jv ? p[jg] : 0.0f;

        if (it == 0 && jv) {            // one tile per column folds the MSE
            const float d = pj - tj;
            macc += d * d;
        }

        if (it < 8 * jt) {
            // ---------- full tile: no i<j predicate ----------
            float s = 0.0f;
            #pragma unroll 8
            for (int ii = 0; ii < TI; ++ii) {
                const float ts = t[ibase + ii];   // wave-uniform -> s_load
                const float ps = p[ibase + ii];
                const float dt = ts - tj;
                const float dp = ps - pj;
                const unsigned sg = __float_as_uint(dt) & 0x80000000u;
                const float sdp = __uint_as_float(__float_as_uint(dp) ^ sg);
                const float v = fmaxf(MARGIN - sdp, 0.0f);
                s += v;
                const bool eq = (dt == 0.0f) && jv;
                if (__any(eq)) {                  // rare exact-tie path
                    s    -= eq ? v : 0.0f;
                    cacc -= eq ? 1 : 0;
                }
            }
            if (jv) { sacc += s; cacc += TI; }
        } else {
            // ---------- partial tile: global i<j predicate ----------
            const int ilim = min(TI, B - ibase);
            const int jloc = jg - ibase;          // valid iff ii < jloc
            float s = 0.0f;
            #pragma unroll 4
            for (int ii = 0; ii < ilim; ++ii) {
                const float ts = t[ibase + ii];
                const float ps = p[ibase + ii];
                const float dt = ts - tj;
                const float dp = ps - pj;
                const unsigned sg = __float_as_uint(dt) & 0x80000000u;
                const float sdp = __uint_as_float(__float_as_uint(dp) ^ sg);
                const float v = fmaxf(MARGIN - sdp, 0.0f);
                const bool inr = (ii < jloc) && jv;
                s += inr ? v : 0.0f;
                const bool eq = (dt == 0.0f) && inr;
                if (__any(eq)) {
                    s    -= eq ? v : 0.0f;
                    cacc -= eq ? 1 : 0;
                }
            }
            sacc += s;
            int c = min(jloc, ilim); c = max(c, 0);
            cacc += jv ? c : 0;
        }
    }

    // block-level reduction -> per-block ws slot
    for (int off = 32; off > 0; off >>= 1) {
        sacc += __shfl_down(sacc, off);
        macc += __shfl_down(macc, off);
        cacc += __shfl_down(cacc, off);
    }
    if (lane == 0) { rs[wid] = sacc; rm[wid] = macc; rc[wid] = cacc; }
    __syncthreads();
    if (tid == 0) {
        bsum[bid] = rs[0] + rs[1] + rs[2] + rs[3];
        bmse[bid] = rm[0] + rm[1] + rm[2] + rm[3];
        bcnt[bid] = rc[0] + rc[1] + rc[2] + rc[3];
    }
    __threadfence();
    cg::this_grid().sync();

    // block 0: fixed-order final reduction (deterministic)
    if (bid == 0) {
        double S = 0.0, M = 0.0;
        long long C = 0;
        for (int k = tid; k < GRID; k += 256) {
            S += (double)bsum[k];
            M += (double)bmse[k];
            C += (long long)bcnt[k];
        }
        for (int off = 32; off > 0; off >>= 1) {
            S += __shfl_down(S, off);
            M += __shfl_down(M, off);
            C += __shfl_down(C, off);
        }
        if (lane == 0) { ds[wid] = S; dm[wid] = M; dc[wid] = C; }
        __syncthreads();
        if (tid == 0) {
            S = ds[0] + ds[1] + ds[2] + ds[3];
            M = dm[0] + dm[1] + dm[2] + dm[3];
            C = dc[0] + dc[1] + dc[2] + dc[3];
            const double mse  = M / (double)B;
            const double rank = (C > 0) ? (S / (double)(C > 1 ? C : 1)) : 0.0;
            out[0] = (float)((double)ALPHA * mse + (double)(1.0f - ALPHA) * rank);
        }
    }
}

extern "C" void kernel_launch(void* const* d_in, const int* in_sizes, int n_in,
                              void* d_out, int out_size, void* d_ws, size_t ws_size,
                              hipStream_t stream) {
    const float* p = (const float*)d_in[0];
    const float* t = (const float*)d_in[1];
    int B = in_sizes[0];

    float* bsum = (float*)d_ws;
    float* bmse = bsum + GRID;
    int*   bcnt = (int*)(bmse + GRID);
    float* out  = (float*)d_out;

    void* args[] = {&p, &t, &B, &bsum, &bmse, &bcnt, &out};
    hipLaunchCooperativeKernel((void*)fused_kernel, dim3(GRID), dim3(256),
                               args, 0, stream);
}

// Round 6
// 21.075 us; speedup vs baseline: 7.2228x; 7.2228x over previous
//
#include <hip/hip_runtime.h>

#define ALPHA  0.7f
#define MARGIN 0.5f
#define TI  64     // i-tile height (wave-uniform scalar loads)
#define TJ  512    // j-tile width = 256 threads * JR
#define JR  2      // j's per thread (float2)

// Triangular tiling, 256-thread blocks.
// Column jt (j in [jt*512, (jt+1)*512)): i-tiles it = 0 .. 8*jt+7 (64 rows).
//   it <  8*jt -> full tile (all i < all j, no predicate)
//   it >= 8*jt -> partial   (per-pair i<j predicate)
// Column start K(jt) = 4*jt*(jt+1). NB = 4*NJ*(NJ+1). B=8192 -> 1088 blocks.
__global__ __launch_bounds__(256, 4)
void pair_kernel(const float* __restrict__ p, const float* __restrict__ t,
                 int B, float* __restrict__ bsum, float* __restrict__ bmse,
                 int* __restrict__ bcnt) {
    const int bid = blockIdx.x;
    int jt = (int)((sqrtf((float)bid + 1.0f) - 1.0f) * 0.5f);
    while (4 * (jt + 1) * (jt + 2) <= bid) ++jt;
    while (4 * jt * (jt + 1) > bid) --jt;
    const int it = bid - 4 * jt * (jt + 1);

    const int tid   = threadIdx.x;         // 0..255
    const int ibase = it * TI;
    const int j0    = jt * TJ + tid * JR;

    // j-data in registers; invalid j padded so hinge==0 and dt!=0:
    //   tj=+inf  -> dt=-inf (never a "tie"), sign=-1 -> sdp=pj-ps=huge>0 -> v=0
    float tjv0, tjv1, pjv0, pjv1;
    bool jv0, jv1;
    if (j0 + JR <= B) {
        const float2 tv = *reinterpret_cast<const float2*>(t + j0);
        const float2 pv = *reinterpret_cast<const float2*>(p + j0);
        tjv0 = tv.x; tjv1 = tv.y; pjv0 = pv.x; pjv1 = pv.y;
        jv0 = jv1 = true;
    } else {
        jv0 = (j0 + 0) < B;
        jv1 = (j0 + 1) < B;
        tjv0 = jv0 ? t[j0]     : __int_as_float(0x7f800000);
        tjv1 = jv1 ? t[j0 + 1] : __int_as_float(0x7f800000);
        pjv0 = jv0 ? p[j0]     : 1e30f;
        pjv1 = jv1 ? p[j0 + 1] : 1e30f;
    }

    float sum = 0.0f, msev = 0.0f;
    int   cnt = 0, tiec = 0;

    if (it == 0) {                       // one tile per column folds the MSE
        const float d0 = pjv0 - tjv0, d1 = pjv1 - tjv1;
        msev += jv0 ? d0 * d0 : 0.0f;
        msev += jv1 ? d1 * d1 : 0.0f;
    }

    const int ilim = min(TI, B - ibase);

    if (it < 8 * jt) {
        // ---------------- full tile: unmasked 8-VALU/pair body ----------------
        #pragma unroll 8
        for (int ii = 0; ii < TI; ++ii) {
            const float ts = t[ibase + ii];     // wave-uniform -> s_load
            const float ps = p[ibase + ii];
            const float dt0 = ts - tjv0;
            const float dp0 = ps - pjv0;
            const float sdp0 = __uint_as_float(__float_as_uint(dp0) ^
                               (__float_as_uint(dt0) & 0x80000000u));
            const float v0 = fmaxf(MARGIN - sdp0, 0.0f);
            sum += v0;
            const float dt1 = ts - tjv1;
            const float dp1 = ps - pjv1;
            const float sdp1 = __uint_as_float(__float_as_uint(dp1) ^
                               (__float_as_uint(dt1) & 0x80000000u));
            const float v1 = fmaxf(MARGIN - sdp1, 0.0f);
            sum += v1;
            const bool e0 = (dt0 == 0.0f);
            const bool e1 = (dt1 == 0.0f);
            if (__any(e0 || e1)) {              // rare exact-tie fixup
                sum  -= e0 ? v0 : 0.0f;
                sum  -= e1 ? v1 : 0.0f;
                tiec += (e0 ? 1 : 0) + (e1 ? 1 : 0);
            }
        }
        cnt += (jv0 ? TI : 0) + (jv1 ? TI : 0);
    } else if (ilim > 0) {
        // ---------------- partial tile: global i<j predicate ----------------
        const int jl0 = j0 - ibase;             // pair valid iff ii < jl0
        const int jl1 = j0 + 1 - ibase;
        #pragma unroll 4
        for (int ii = 0; ii < ilim; ++ii) {
            const float ts = t[ibase + ii];
            const float ps = p[ibase + ii];
            const bool in0 = ii < jl0;
            const bool in1 = ii < jl1;
            const float dt0 = ts - tjv0;
            const float dp0 = ps - pjv0;
            const float sdp0 = __uint_as_float(__float_as_uint(dp0) ^
                               (__float_as_uint(dt0) & 0x80000000u));
            const float v0 = fmaxf(MARGIN - sdp0, 0.0f);
            sum += in0 ? v0 : 0.0f;
            const float dt1 = ts - tjv1;
            const float dp1 = ps - pjv1;
            const float sdp1 = __uint_as_float(__float_as_uint(dp1) ^
                               (__float_as_uint(dt1) & 0x80000000u));
            const float v1 = fmaxf(MARGIN - sdp1, 0.0f);
            sum += in1 ? v1 : 0.0f;
            const bool e0 = (dt0 == 0.0f) && in0;
            const bool e1 = (dt1 == 0.0f) && in1;
            if (__any(e0 || e1)) {              // rare exact-tie fixup
                sum  -= e0 ? v0 : 0.0f;
                sum  -= e1 ? v1 : 0.0f;
                tiec += (e0 ? 1 : 0) + (e1 ? 1 : 0);
            }
        }
        int c0 = min(max(jl0, 0), ilim);
        int c1 = min(max(jl1, 0), ilim);
        cnt += (jv0 ? c0 : 0) + (jv1 ? c1 : 0);
    }

    // epilogue: wave butterfly, then cross-wave via LDS
    int cn = cnt - tiec;
    for (int off = 32; off > 0; off >>= 1) {
        sum  += __shfl_down(sum, off);
        msev += __shfl_down(msev, off);
        cn   += __shfl_down(cn, off);
    }
    __shared__ float rs[4], rm[4];
    __shared__ int   rc[4];
    const int wid = tid >> 6, lane = tid & 63;
    if (lane == 0) { rs[wid] = sum; rm[wid] = msev; rc[wid] = cn; }
    __syncthreads();
    if (tid == 0) {
        bsum[bid] = rs[0] + rs[1] + rs[2] + rs[3];
        bmse[bid] = rm[0] + rm[1] + rm[2] + rm[3];
        bcnt[bid] = rc[0] + rc[1] + rc[2] + rc[3];
    }
}

// Fixed-order deterministic tree reduction over NB partials.
__global__ __launch_bounds__(256) void finalize_kernel(const float* __restrict__ bsum,
                                                       const float* __restrict__ bmse,
                                                       const int*   __restrict__ bcnt,
                                                       int NB, int B,
                                                       float* __restrict__ out) {
    const int tid = threadIdx.x;
    double S = 0.0, M = 0.0;
    long long C = 0;
    for (int k = tid; k < NB; k += 256) {
        S += (double)bsum[k];
        M += (double)bmse[k];
        C += (long long)bcnt[k];
    }
    for (int off = 32; off > 0; off >>= 1) {
        S += __shfl_down(S, off);
        M += __shfl_down(M, off);
        C += __shfl_down(C, off);
    }
    __shared__ double rs[4], rm[4];
    __shared__ long long rc[4];
    const int wid = tid >> 6, lane = tid & 63;
    if (lane == 0) { rs[wid] = S; rm[wid] = M; rc[wid] = C; }
    __syncthreads();
    if (tid == 0) {
        S = rs[0] + rs[1] + rs[2] + rs[3];
        M = rm[0] + rm[1] + rm[2] + rm[3];
        C = rc[0] + rc[1] + rc[2] + rc[3];
        const double mse  = M / (double)B;
        const double rank = (C > 0) ? (S / (double)(C > 1 ? C : 1)) : 0.0;
        out[0] = (float)((double)ALPHA * mse + (double)(1.0f - ALPHA) * rank);
    }
}

extern "C" void kernel_launch(void* const* d_in, const int* in_sizes, int n_in,
                              void* d_out, int out_size, void* d_ws, size_t ws_size,
                              hipStream_t stream) {
    const float* p = (const float*)d_in[0];
    const float* t = (const float*)d_in[1];
    const int B = in_sizes[0];

    const int NJ = (B + TJ - 1) / TJ;
    const int NB = 4 * NJ * (NJ + 1);

    float* bsum = (float*)d_ws;
    float* bmse = bsum + NB;
    int*   bcnt = (int*)(bmse + NB);

    pair_kernel<<<NB, 256, 0, stream>>>(p, t, B, bsum, bmse, bcnt);
    finalize_kernel<<<1, 256, 0, stream>>>(bsum, bmse, bcnt, NB, B, (float*)d_out);
}